// Round 1
// baseline (1063.605 us; speedup 1.0000x reference)
//
#include <hip/hip_runtime.h>

#define EMBED_DIM 128

// ---------------------------------------------------------------------------
// GCN message passing:
//   deg[c] = (#edges into c) + 1 (self loop)
//   dis = rsqrt(deg)
//   out[c] = bias + dis[c]^2 * x[c] + sum_e{col[e]==c} dis[row[e]]*dis[c]*x[row[e]]
//   second output = x (identity init embedding)
// ---------------------------------------------------------------------------

__global__ void k_init_deg(float* __restrict__ deg, int n) {
    int i = blockIdx.x * blockDim.x + threadIdx.x;
    if (i < n) deg[i] = 1.0f;  // self loop
}

__global__ void k_count_deg(const int* __restrict__ col, float* __restrict__ deg, int e) {
    int i = blockIdx.x * blockDim.x + threadIdx.x;
    if (i < e) unsafeAtomicAdd(&deg[col[i]], 1.0f);
}

__global__ void k_rsqrt(float* __restrict__ deg, int n) {
    int i = blockIdx.x * blockDim.x + threadIdx.x;
    if (i < n) deg[i] = rsqrtf(deg[i]);  // deg >= 1 always
}

// One float4 per thread: out = bias + dis^2 * x  (self-loop term), out2 = x.
__global__ void k_init_out(const float* __restrict__ x, const float* __restrict__ bias,
                           const float* __restrict__ dis, float* __restrict__ out,
                           float* __restrict__ out2, int n) {
    int gid = blockIdx.x * blockDim.x + threadIdx.x;
    int total = n * (EMBED_DIM / 4);
    if (gid >= total) return;
    int node = gid >> 5;        // / 32
    int q    = gid & 31;        // float4 index within row
    float4 xv = reinterpret_cast<const float4*>(x)[gid];
    float4 bv = reinterpret_cast<const float4*>(bias)[q];
    float s = dis[node];
    s = s * s;
    float4 ov;
    ov.x = bv.x + s * xv.x;
    ov.y = bv.y + s * xv.y;
    ov.z = bv.z + s * xv.z;
    ov.w = bv.w + s * xv.w;
    reinterpret_cast<float4*>(out)[gid]  = ov;
    reinterpret_cast<float4*>(out2)[gid] = xv;  // init_embeds = x
}

// 32 threads per edge, each handles one float4 (4 scalar atomic adds).
__global__ void k_scatter(const int* __restrict__ row, const int* __restrict__ col,
                          const float* __restrict__ x, const float* __restrict__ dis,
                          float* __restrict__ out, int e) {
    int gid = blockIdx.x * blockDim.x + threadIdx.x;
    int total = e * 32;
    if (gid >= total) return;
    int edge = gid >> 5;
    int q    = gid & 31;
    int r = row[edge];
    int c = col[edge];
    float w = dis[r] * dis[c];
    float4 xv = reinterpret_cast<const float4*>(x + (size_t)r * EMBED_DIM)[q];
    float* o = out + (size_t)c * EMBED_DIM + q * 4;
    unsafeAtomicAdd(o + 0, w * xv.x);
    unsafeAtomicAdd(o + 1, w * xv.y);
    unsafeAtomicAdd(o + 2, w * xv.z);
    unsafeAtomicAdd(o + 3, w * xv.w);
}

extern "C" void kernel_launch(void* const* d_in, const int* in_sizes, int n_in,
                              void* d_out, int out_size, void* d_ws, size_t ws_size,
                              hipStream_t stream) {
    const float* x    = (const float*)d_in[0];
    const int*   idx  = (const int*)d_in[1];   // [2, E] int32 on device
    const float* bias = (const float*)d_in[2];

    const int n = in_sizes[0] / EMBED_DIM;     // 50000
    const int e = in_sizes[1] / 2;             // 600000

    const int* row = idx;                      // edge_index[0] = sources
    const int* col = idx + e;                  // edge_index[1] = destinations

    float* out  = (float*)d_out;                         // [n, 128]
    float* out2 = (float*)d_out + (size_t)n * EMBED_DIM; // init_embeds = x

    float* deg = (float*)d_ws;                 // n floats; becomes dis in-place

    const int B = 256;

    k_init_deg<<<(n + B - 1) / B, B, 0, stream>>>(deg, n);
    k_count_deg<<<(e + B - 1) / B, B, 0, stream>>>(col, deg, e);
    k_rsqrt<<<(n + B - 1) / B, B, 0, stream>>>(deg, n);

    int init_threads = n * (EMBED_DIM / 4);
    k_init_out<<<(init_threads + B - 1) / B, B, 0, stream>>>(x, bias, deg, out, out2, n);

    int scat_threads = e * 32;
    k_scatter<<<(scat_threads + B - 1) / B, B, 0, stream>>>(row, col, x, deg, out, e);
}

// Round 2
// 128.377 us; speedup vs baseline: 8.2850x; 8.2850x over previous
//
#include <hip/hip_runtime.h>

#define D 128
#define B 256

// ---------------------------------------------------------------------------
// GCN message passing via on-the-fly CSR (counting sort by destination):
//   1. degInt[c] = #edges into c                (int atomics)
//   2. off = exclusive_scan(degInt)             (3-kernel scan)
//      dis[i] = rsqrt(degInt[i] + 1)            (self loop included in deg)
//   3. ssrc[off[c] + k] = row of k-th edge to c (placement, int atomics)
//   4. gather: out[c] = bias + dis[c]*( sum_r dis[r]*x[r] + dis[c]*x[c] )
//      out2 = x
// ---------------------------------------------------------------------------

__global__ void k_zero(int* __restrict__ degInt, int* __restrict__ cursor, int n) {
    int i = blockIdx.x * blockDim.x + threadIdx.x;
    if (i < n) { degInt[i] = 0; cursor[i] = 0; }
}

__global__ void k_count(const int* __restrict__ col, int* __restrict__ degInt, int e) {
    int i = blockIdx.x * blockDim.x + threadIdx.x;
    if (i < e) atomicAdd(&degInt[col[i]], 1);
}

// Per-block exclusive scan of 256 elements; block totals to bsum.
__global__ void k_scan1(const int* __restrict__ degInt, int* __restrict__ off,
                        int* __restrict__ bsum, int n) {
    __shared__ int sm[B];
    int i = blockIdx.x * B + threadIdx.x;
    int v = (i < n) ? degInt[i] : 0;
    sm[threadIdx.x] = v;
    __syncthreads();
    for (int s = 1; s < B; s <<= 1) {
        int t = (threadIdx.x >= (unsigned)s) ? sm[threadIdx.x - s] : 0;
        __syncthreads();
        sm[threadIdx.x] += t;
        __syncthreads();
    }
    if (i < n) off[i] = sm[threadIdx.x] - v;          // exclusive within block
    if (threadIdx.x == B - 1) bsum[blockIdx.x] = sm[B - 1];
}

// Single-block exclusive scan of block sums (nb <= 256).
__global__ void k_scan2(int* __restrict__ bsum, int nb) {
    __shared__ int sm[B];
    int v = (threadIdx.x < (unsigned)nb) ? bsum[threadIdx.x] : 0;
    sm[threadIdx.x] = v;
    __syncthreads();
    for (int s = 1; s < B; s <<= 1) {
        int t = (threadIdx.x >= (unsigned)s) ? sm[threadIdx.x - s] : 0;
        __syncthreads();
        sm[threadIdx.x] += t;
        __syncthreads();
    }
    if (threadIdx.x < (unsigned)nb) bsum[threadIdx.x] = sm[threadIdx.x] - v;
}

// Add block offsets; also produce dis[] and off[n].
__global__ void k_scan3(int* __restrict__ off, const int* __restrict__ bsum,
                        const int* __restrict__ degInt, float* __restrict__ dis,
                        int n, int e) {
    int i = blockIdx.x * B + threadIdx.x;
    if (i < n) {
        off[i] += bsum[blockIdx.x];
        dis[i] = rsqrtf((float)degInt[i] + 1.0f);   // +1 self loop
    }
    if (i == 0) off[n] = e;
}

__global__ void k_place(const int* __restrict__ row, const int* __restrict__ col,
                        const int* __restrict__ off, int* __restrict__ cursor,
                        int* __restrict__ ssrc, int e) {
    int i = blockIdx.x * blockDim.x + threadIdx.x;
    if (i >= e) return;
    int c = col[i];
    int pos = off[c] + atomicAdd(&cursor[c], 1);
    ssrc[pos] = row[i];
}

// 32 threads per destination node; each owns one float4 of the 128-dim row.
__global__ void k_aggregate(const float* __restrict__ x, const float* __restrict__ bias,
                            const float* __restrict__ dis, const int* __restrict__ off,
                            const int* __restrict__ ssrc, float* __restrict__ out,
                            float* __restrict__ out2, int n) {
    int gid = blockIdx.x * blockDim.x + threadIdx.x;
    if (gid >= n * 32) return;
    int node = gid >> 5;
    int q    = gid & 31;

    const float4* x4 = reinterpret_cast<const float4*>(x);

    int start = off[node];
    int end   = off[node + 1];

    float4 acc = make_float4(0.f, 0.f, 0.f, 0.f);
    for (int j = start; j < end; ++j) {
        int r = ssrc[j];                       // broadcast across the 32 lanes
        float w = dis[r];
        float4 xv = x4[(size_t)r * 32 + q];
        acc.x += w * xv.x;
        acc.y += w * xv.y;
        acc.z += w * xv.z;
        acc.w += w * xv.w;
    }

    float dc = dis[node];
    float4 xc = x4[(size_t)node * 32 + q];
    float4 bv = reinterpret_cast<const float4*>(bias)[q];
    float4 ov;
    ov.x = bv.x + dc * (acc.x + dc * xc.x);
    ov.y = bv.y + dc * (acc.y + dc * xc.y);
    ov.z = bv.z + dc * (acc.z + dc * xc.z);
    ov.w = bv.w + dc * (acc.w + dc * xc.w);

    float4* out4  = reinterpret_cast<float4*>(out);
    float4* out24 = reinterpret_cast<float4*>(out2);
    out4[(size_t)node * 32 + q]  = ov;
    out24[(size_t)node * 32 + q] = xc;         // init_embeds = x
}

extern "C" void kernel_launch(void* const* d_in, const int* in_sizes, int n_in,
                              void* d_out, int out_size, void* d_ws, size_t ws_size,
                              hipStream_t stream) {
    const float* x    = (const float*)d_in[0];
    const int*   idx  = (const int*)d_in[1];   // [2, E]
    const float* bias = (const float*)d_in[2];

    const int n = in_sizes[0] / D;             // 50000
    const int e = in_sizes[1] / 2;             // 600000

    const int* row = idx;                      // sources
    const int* col = idx + e;                  // destinations

    float* out  = (float*)d_out;                     // [n, 128]
    float* out2 = (float*)d_out + (size_t)n * D;     // init_embeds

    // workspace layout (all 4-byte aligned)
    int*   degInt = (int*)d_ws;                // n
    int*   cursor = degInt + n;                // n
    int*   off    = cursor + n;                // n+1
    int*   bsum   = off + n + 1;               // up to 256
    float* dis    = (float*)(bsum + 256);      // n
    int*   ssrc   = (int*)(dis + n);           // e

    const int nbN = (n + B - 1) / B;           // 196 blocks over nodes
    const int nbE = (e + B - 1) / B;

    k_zero <<<nbN, B, 0, stream>>>(degInt, cursor, n);
    k_count<<<nbE, B, 0, stream>>>(col, degInt, e);
    k_scan1<<<nbN, B, 0, stream>>>(degInt, off, bsum, n);
    k_scan2<<<1,   B, 0, stream>>>(bsum, nbN);
    k_scan3<<<nbN, B, 0, stream>>>(off, bsum, degInt, dis, n, e);
    k_place<<<nbE, B, 0, stream>>>(row, col, off, cursor, ssrc, e);

    int aggT = n * 32;
    k_aggregate<<<(aggT + B - 1) / B, B, 0, stream>>>(x, bias, dis, off, ssrc, out, out2, n);
}

// Round 4
// 126.873 us; speedup vs baseline: 8.3832x; 1.0118x over previous
//
#include <hip/hip_runtime.h>

#define D 128
#define B 256

typedef float vfloat4 __attribute__((ext_vector_type(4)));

// ---------------------------------------------------------------------------
// GCN message passing via on-the-fly CSR (counting sort by destination):
//   1. degInt[c] = #edges into c                 (int atomics)
//   2. off = exclusive_scan(degInt); dis = rsqrt(deg+1); cursor = off
//   3. pairs[cursor[c]++] = (row, dis[row])      (placement, int atomics)
//   4. gather: out[c] = bias + dis[c]*( sum_j w_j*x[r_j] + dis[c]*x[c] )
//      out2 = x
// ---------------------------------------------------------------------------

__global__ void k_zero(int* __restrict__ degInt, int n) {
    int i = blockIdx.x * blockDim.x + threadIdx.x;
    if (i < n) degInt[i] = 0;
}

__global__ void k_count(const int* __restrict__ col, int* __restrict__ degInt, int e) {
    int i = blockIdx.x * blockDim.x + threadIdx.x;
    if (i < e) atomicAdd(&degInt[col[i]], 1);
}

// Per-block exclusive scan of 256 elements; block totals to bsum.
__global__ void k_scan1(const int* __restrict__ degInt, int* __restrict__ off,
                        int* __restrict__ bsum, int n) {
    __shared__ int sm[B];
    int i = blockIdx.x * B + threadIdx.x;
    int v = (i < n) ? degInt[i] : 0;
    sm[threadIdx.x] = v;
    __syncthreads();
    for (int s = 1; s < B; s <<= 1) {
        int t = (threadIdx.x >= (unsigned)s) ? sm[threadIdx.x - s] : 0;
        __syncthreads();
        sm[threadIdx.x] += t;
        __syncthreads();
    }
    if (i < n) off[i] = sm[threadIdx.x] - v;          // exclusive within block
    if (threadIdx.x == B - 1) bsum[blockIdx.x] = sm[B - 1];
}

// Single-block exclusive scan of block sums (nb <= 256).
__global__ void k_scan2(int* __restrict__ bsum, int nb) {
    __shared__ int sm[B];
    int v = (threadIdx.x < (unsigned)nb) ? bsum[threadIdx.x] : 0;
    sm[threadIdx.x] = v;
    __syncthreads();
    for (int s = 1; s < B; s <<= 1) {
        int t = (threadIdx.x >= (unsigned)s) ? sm[threadIdx.x - s] : 0;
        __syncthreads();
        sm[threadIdx.x] += t;
        __syncthreads();
    }
    if (threadIdx.x < (unsigned)nb) bsum[threadIdx.x] = sm[threadIdx.x] - v;
}

// Add block offsets; produce dis[], cursor = off, off[n] = e.
__global__ void k_scan3(int* __restrict__ off, const int* __restrict__ bsum,
                        const int* __restrict__ degInt, float* __restrict__ dis,
                        int* __restrict__ cursor, int n, int e) {
    int i = blockIdx.x * B + threadIdx.x;
    if (i < n) {
        int o = off[i] + bsum[blockIdx.x];
        off[i] = o;
        cursor[i] = o;
        dis[i] = rsqrtf((float)degInt[i] + 1.0f);   // +1 self loop
    }
    if (i == 0) off[n] = e;
}

// Packed path: pairs[pos] = (src, dis[src] bits). Single random atomic per edge.
__global__ void k_place_pairs(const int* __restrict__ row, const int* __restrict__ col,
                              const float* __restrict__ dis, int* __restrict__ cursor,
                              int2* __restrict__ pairs, int e) {
    int i = blockIdx.x * blockDim.x + threadIdx.x;
    if (i >= e) return;
    int r = row[i];
    int c = col[i];
    float w = dis[r];
    int pos = atomicAdd(&cursor[c], 1);
    pairs[pos] = make_int2(r, __float_as_int(w));
}

// 32 threads per destination node; each owns one float4 of the 128-dim row.
// Edge loop unrolled x4 with independent accumulators for MLP.
__global__ void k_aggregate_pairs(const float* __restrict__ x, const float* __restrict__ bias,
                                  const float* __restrict__ dis, const int* __restrict__ off,
                                  const int2* __restrict__ pairs, float* __restrict__ out,
                                  float* __restrict__ out2, int n) {
    int gid = blockIdx.x * blockDim.x + threadIdx.x;
    if (gid >= n * 32) return;
    int node = gid >> 5;
    int q    = gid & 31;

    const vfloat4* x4 = reinterpret_cast<const vfloat4*>(x);

    int j   = off[node];
    int end = off[node + 1];

    vfloat4 a0 = {0.f, 0.f, 0.f, 0.f};
    vfloat4 a1 = a0, a2 = a0, a3 = a0;

    for (; j + 4 <= end; j += 4) {
        int2 p0 = pairs[j + 0];
        int2 p1 = pairs[j + 1];
        int2 p2 = pairs[j + 2];
        int2 p3 = pairs[j + 3];
        vfloat4 v0 = x4[(size_t)p0.x * 32 + q];
        vfloat4 v1 = x4[(size_t)p1.x * 32 + q];
        vfloat4 v2 = x4[(size_t)p2.x * 32 + q];
        vfloat4 v3 = x4[(size_t)p3.x * 32 + q];
        float w0 = __int_as_float(p0.y), w1 = __int_as_float(p1.y);
        float w2 = __int_as_float(p2.y), w3 = __int_as_float(p3.y);
        a0 += w0 * v0;
        a1 += w1 * v1;
        a2 += w2 * v2;
        a3 += w3 * v3;
    }
    for (; j < end; ++j) {
        int2 p = pairs[j];
        vfloat4 v = x4[(size_t)p.x * 32 + q];
        float w = __int_as_float(p.y);
        a0 += w * v;
    }

    float dc = dis[node];
    vfloat4 xc = x4[(size_t)node * 32 + q];
    vfloat4 bv = reinterpret_cast<const vfloat4*>(bias)[q];
    vfloat4 ov = bv + dc * (a0 + a1 + a2 + a3 + dc * xc);

    // Non-temporal: out/out2 are write-once, keep them out of L2 so x stays hot.
    __builtin_nontemporal_store(ov, reinterpret_cast<vfloat4*>(out)  + (size_t)node * 32 + q);
    __builtin_nontemporal_store(xc, reinterpret_cast<vfloat4*>(out2) + (size_t)node * 32 + q);
}

// ---- fallback (small ws): int-only CSR ----
__global__ void k_place_int(const int* __restrict__ row, const int* __restrict__ col,
                            int* __restrict__ cursor, int* __restrict__ ssrc, int e) {
    int i = blockIdx.x * blockDim.x + threadIdx.x;
    if (i >= e) return;
    int pos = atomicAdd(&cursor[col[i]], 1);
    ssrc[pos] = row[i];
}

__global__ void k_aggregate_int(const float* __restrict__ x, const float* __restrict__ bias,
                                const float* __restrict__ dis, const int* __restrict__ off,
                                const int* __restrict__ ssrc, float* __restrict__ out,
                                float* __restrict__ out2, int n) {
    int gid = blockIdx.x * blockDim.x + threadIdx.x;
    if (gid >= n * 32) return;
    int node = gid >> 5;
    int q    = gid & 31;
    const vfloat4* x4 = reinterpret_cast<const vfloat4*>(x);
    int j = off[node], end = off[node + 1];
    vfloat4 a0 = {0.f, 0.f, 0.f, 0.f};
    for (; j < end; ++j) {
        int r = ssrc[j];
        float w = dis[r];
        a0 += w * x4[(size_t)r * 32 + q];
    }
    float dc = dis[node];
    vfloat4 xc = x4[(size_t)node * 32 + q];
    vfloat4 bv = reinterpret_cast<const vfloat4*>(bias)[q];
    vfloat4 ov = bv + dc * (a0 + dc * xc);
    reinterpret_cast<vfloat4*>(out)[(size_t)node * 32 + q]  = ov;
    reinterpret_cast<vfloat4*>(out2)[(size_t)node * 32 + q] = xc;
}

extern "C" void kernel_launch(void* const* d_in, const int* in_sizes, int n_in,
                              void* d_out, int out_size, void* d_ws, size_t ws_size,
                              hipStream_t stream) {
    const float* x    = (const float*)d_in[0];
    const int*   idx  = (const int*)d_in[1];   // [2, E]
    const float* bias = (const float*)d_in[2];

    const int n = in_sizes[0] / D;             // 50000
    const int e = in_sizes[1] / 2;             // 600000

    const int* row = idx;                      // sources
    const int* col = idx + e;                  // destinations

    float* out  = (float*)d_out;                     // [n, 128]
    float* out2 = (float*)d_out + (size_t)n * D;     // init_embeds

    // workspace layout
    char* p = (char*)d_ws;
    int*   degInt = (int*)p;            p += (size_t)n * 4;
    int*   cursor = (int*)p;            p += (size_t)n * 4;
    int*   off    = (int*)p;            p += (size_t)(n + 1) * 4;
    int*   bsum   = (int*)p;            p += 256 * 4;
    float* dis    = (float*)p;          p += (size_t)n * 4;
    // align to 16 for pairs
    p = (char*)(((uintptr_t)p + 15) & ~(uintptr_t)15);
    int2*  pairs  = (int2*)p;           // e * 8 bytes (packed path)
    int*   ssrc   = (int*)p;            // e * 4 bytes (fallback path)

    size_t needed_pairs = (size_t)(p - (char*)d_ws) + (size_t)e * 8;
    bool use_pairs = ws_size >= needed_pairs;

    const int nbN = (n + B - 1) / B;
    const int nbE = (e + B - 1) / B;

    k_zero <<<nbN, B, 0, stream>>>(degInt, n);
    k_count<<<nbE, B, 0, stream>>>(col, degInt, e);
    k_scan1<<<nbN, B, 0, stream>>>(degInt, off, bsum, n);
    k_scan2<<<1,   B, 0, stream>>>(bsum, nbN);
    k_scan3<<<nbN, B, 0, stream>>>(off, bsum, degInt, dis, cursor, n, e);

    int aggT = n * 32;
    if (use_pairs) {
        k_place_pairs<<<nbE, B, 0, stream>>>(row, col, dis, cursor, pairs, e);
        k_aggregate_pairs<<<(aggT + B - 1) / B, B, 0, stream>>>(x, bias, dis, off, pairs,
                                                                out, out2, n);
    } else {
        k_place_int<<<nbE, B, 0, stream>>>(row, col, cursor, ssrc, e);
        k_aggregate_int<<<(aggT + B - 1) / B, B, 0, stream>>>(x, bias, dis, off, ssrc,
                                                              out, out2, n);
    }
}

// Round 5
// 84.335 us; speedup vs baseline: 12.6117x; 1.5044x over previous
//
#include <hip/hip_runtime.h>

#define D 128
#define B 256
#define WMAX 64
#define SPILL_MAX 8192

typedef float vfloat4 __attribute__((ext_vector_type(4)));

// ---------------------------------------------------------------------------
// GCN message passing, ELL + bf16-gather edition:
//   prep : cursor=0, out2=x (NT), xb=bf16(x)
//   place: pos = cursor[c]++;  ssrc[c*64+pos] = r   (spill list if pos>=64)
//   agg  : out[c] = bias + dc*( sum_j rsqrt(deg_rj+1)*xb[r_j] + dc*xb[c] ),
//          dc = rsqrt(cursor[c]+1)    [cursor == in-degree after place]
//   spill: atomic fp32 adds for the (normally zero) overflow edges
// Fallback (small ws): round-4 CSR-pairs pipeline.
// ---------------------------------------------------------------------------

__device__ __forceinline__ unsigned short f2bf(float f) {   // RTNE f32->bf16
    unsigned u = __float_as_uint(f);
    u = u + 0x7FFFu + ((u >> 16) & 1u);
    return (unsigned short)(u >> 16);
}

__device__ __forceinline__ vfloat4 bf2f4(uint2 v) {
    vfloat4 r;
    r.x = __uint_as_float(v.x << 16);
    r.y = __uint_as_float(v.x & 0xffff0000u);
    r.z = __uint_as_float(v.y << 16);
    r.w = __uint_as_float(v.y & 0xffff0000u);
    return r;
}

__global__ void k_prep(const float* __restrict__ x, float* __restrict__ out2,
                       uint2* __restrict__ xb, int* __restrict__ cursor,
                       int* __restrict__ spillCnt, int n) {
    int gid = blockIdx.x * blockDim.x + threadIdx.x;
    if (gid == 0) *spillCnt = 0;
    if (gid < n) cursor[gid] = 0;
    if (gid >= n * 32) return;
    vfloat4 xv = reinterpret_cast<const vfloat4*>(x)[gid];
    __builtin_nontemporal_store(xv, reinterpret_cast<vfloat4*>(out2) + gid);
    uint2 b;
    b.x = (unsigned)f2bf(xv.x) | ((unsigned)f2bf(xv.y) << 16);
    b.y = (unsigned)f2bf(xv.z) | ((unsigned)f2bf(xv.w) << 16);
    xb[gid] = b;
}

__global__ void k_place_ell(const int* __restrict__ row, const int* __restrict__ col,
                            int* __restrict__ cursor, int* __restrict__ ssrc,
                            int2* __restrict__ spill, int* __restrict__ spillCnt, int e) {
    int i = blockIdx.x * blockDim.x + threadIdx.x;
    if (i >= e) return;
    int r = row[i];
    int c = col[i];
    int pos = atomicAdd(&cursor[c], 1);
    if (pos < WMAX) {
        ssrc[(size_t)c * WMAX + pos] = r;
    } else {
        int s = atomicAdd(spillCnt, 1);
        if (s < SPILL_MAX) spill[s] = make_int2(r, c);
    }
}

// 32 lanes per node, 8B bf16 gather per lane, x4 unrolled.
__global__ void k_agg_ell(const uint2* __restrict__ xb, const float* __restrict__ bias,
                          const int* __restrict__ cursor, const int* __restrict__ ssrc,
                          float* __restrict__ out, int n) {
    int gid = blockIdx.x * blockDim.x + threadIdx.x;
    if (gid >= n * 32) return;
    int node = gid >> 5;
    int q    = gid & 31;

    int cnt = cursor[node];
    int m   = min(cnt, WMAX);
    const int* sp = ssrc + (size_t)node * WMAX;

    vfloat4 a0 = {0.f, 0.f, 0.f, 0.f};
    vfloat4 a1 = a0, a2 = a0, a3 = a0;

    int j = 0;
    for (; j + 4 <= m; j += 4) {
        int r0 = sp[j + 0], r1 = sp[j + 1], r2 = sp[j + 2], r3 = sp[j + 3];
        uint2 v0 = xb[(size_t)r0 * 32 + q];
        uint2 v1 = xb[(size_t)r1 * 32 + q];
        uint2 v2 = xb[(size_t)r2 * 32 + q];
        uint2 v3 = xb[(size_t)r3 * 32 + q];
        float w0 = rsqrtf((float)cursor[r0] + 1.0f);
        float w1 = rsqrtf((float)cursor[r1] + 1.0f);
        float w2 = rsqrtf((float)cursor[r2] + 1.0f);
        float w3 = rsqrtf((float)cursor[r3] + 1.0f);
        a0 += w0 * bf2f4(v0);
        a1 += w1 * bf2f4(v1);
        a2 += w2 * bf2f4(v2);
        a3 += w3 * bf2f4(v3);
    }
    for (; j < m; ++j) {
        int r = sp[j];
        uint2 v = xb[(size_t)r * 32 + q];
        float w = rsqrtf((float)cursor[r] + 1.0f);
        a0 += w * bf2f4(v);
    }

    float dc = rsqrtf((float)cnt + 1.0f);
    vfloat4 xc = bf2f4(xb[(size_t)node * 32 + q]);
    vfloat4 bv = reinterpret_cast<const vfloat4*>(bias)[q];
    vfloat4 ov = bv + dc * (a0 + a1 + a2 + a3 + dc * xc);

    __builtin_nontemporal_store(ov, reinterpret_cast<vfloat4*>(out) + (size_t)node * 32 + q);
}

// Handles edges whose node exceeded WMAX in-degree (normally zero edges).
__global__ void k_spill(const float* __restrict__ x, const int* __restrict__ cursor,
                        const int2* __restrict__ spill, const int* __restrict__ spillCnt,
                        float* __restrict__ out) {
    int t = blockIdx.x * blockDim.x + threadIdx.x;
    int cnt = min(*spillCnt, SPILL_MAX);
    int edge = t >> 5;
    if (edge >= cnt) return;
    int q = t & 31;
    int2 p = spill[edge];
    float w = rsqrtf((float)cursor[p.x] + 1.0f) * rsqrtf((float)cursor[p.y] + 1.0f);
    vfloat4 xv = reinterpret_cast<const vfloat4*>(x)[(size_t)p.x * 32 + q];
    float* o = out + (size_t)p.y * D + q * 4;
    unsafeAtomicAdd(o + 0, w * xv.x);
    unsafeAtomicAdd(o + 1, w * xv.y);
    unsafeAtomicAdd(o + 2, w * xv.z);
    unsafeAtomicAdd(o + 3, w * xv.w);
}

// ======================= fallback: round-4 CSR pipeline =======================

__global__ void k_zero(int* __restrict__ degInt, int n) {
    int i = blockIdx.x * blockDim.x + threadIdx.x;
    if (i < n) degInt[i] = 0;
}

__global__ void k_count(const int* __restrict__ col, int* __restrict__ degInt, int e) {
    int i = blockIdx.x * blockDim.x + threadIdx.x;
    if (i < e) atomicAdd(&degInt[col[i]], 1);
}

__global__ void k_scan1(const int* __restrict__ degInt, int* __restrict__ off,
                        int* __restrict__ bsum, int n) {
    __shared__ int sm[B];
    int i = blockIdx.x * B + threadIdx.x;
    int v = (i < n) ? degInt[i] : 0;
    sm[threadIdx.x] = v;
    __syncthreads();
    for (int s = 1; s < B; s <<= 1) {
        int t = (threadIdx.x >= (unsigned)s) ? sm[threadIdx.x - s] : 0;
        __syncthreads();
        sm[threadIdx.x] += t;
        __syncthreads();
    }
    if (i < n) off[i] = sm[threadIdx.x] - v;
    if (threadIdx.x == B - 1) bsum[blockIdx.x] = sm[B - 1];
}

__global__ void k_scan2(int* __restrict__ bsum, int nb) {
    __shared__ int sm[B];
    int v = (threadIdx.x < (unsigned)nb) ? bsum[threadIdx.x] : 0;
    sm[threadIdx.x] = v;
    __syncthreads();
    for (int s = 1; s < B; s <<= 1) {
        int t = (threadIdx.x >= (unsigned)s) ? sm[threadIdx.x - s] : 0;
        __syncthreads();
        sm[threadIdx.x] += t;
        __syncthreads();
    }
    if (threadIdx.x < (unsigned)nb) bsum[threadIdx.x] = sm[threadIdx.x] - v;
}

__global__ void k_scan3(int* __restrict__ off, const int* __restrict__ bsum,
                        const int* __restrict__ degInt, float* __restrict__ dis,
                        int* __restrict__ cursor, int n, int e) {
    int i = blockIdx.x * B + threadIdx.x;
    if (i < n) {
        int o = off[i] + bsum[blockIdx.x];
        off[i] = o;
        cursor[i] = o;
        dis[i] = rsqrtf((float)degInt[i] + 1.0f);
    }
    if (i == 0) off[n] = e;
}

__global__ void k_place_pairs(const int* __restrict__ row, const int* __restrict__ col,
                              const float* __restrict__ dis, int* __restrict__ cursor,
                              int2* __restrict__ pairs, int e) {
    int i = blockIdx.x * blockDim.x + threadIdx.x;
    if (i >= e) return;
    int r = row[i];
    int c = col[i];
    float w = dis[r];
    int pos = atomicAdd(&cursor[c], 1);
    pairs[pos] = make_int2(r, __float_as_int(w));
}

__global__ void k_aggregate_pairs(const float* __restrict__ x, const float* __restrict__ bias,
                                  const float* __restrict__ dis, const int* __restrict__ off,
                                  const int2* __restrict__ pairs, float* __restrict__ out,
                                  float* __restrict__ out2, int n) {
    int gid = blockIdx.x * blockDim.x + threadIdx.x;
    if (gid >= n * 32) return;
    int node = gid >> 5;
    int q    = gid & 31;
    const vfloat4* x4 = reinterpret_cast<const vfloat4*>(x);
    int j   = off[node];
    int end = off[node + 1];
    vfloat4 a0 = {0.f, 0.f, 0.f, 0.f};
    vfloat4 a1 = a0, a2 = a0, a3 = a0;
    for (; j + 4 <= end; j += 4) {
        int2 p0 = pairs[j + 0];
        int2 p1 = pairs[j + 1];
        int2 p2 = pairs[j + 2];
        int2 p3 = pairs[j + 3];
        vfloat4 v0 = x4[(size_t)p0.x * 32 + q];
        vfloat4 v1 = x4[(size_t)p1.x * 32 + q];
        vfloat4 v2 = x4[(size_t)p2.x * 32 + q];
        vfloat4 v3 = x4[(size_t)p3.x * 32 + q];
        a0 += __int_as_float(p0.y) * v0;
        a1 += __int_as_float(p1.y) * v1;
        a2 += __int_as_float(p2.y) * v2;
        a3 += __int_as_float(p3.y) * v3;
    }
    for (; j < end; ++j) {
        int2 p = pairs[j];
        a0 += __int_as_float(p.y) * x4[(size_t)p.x * 32 + q];
    }
    float dc = dis[node];
    vfloat4 xc = x4[(size_t)node * 32 + q];
    vfloat4 bv = reinterpret_cast<const vfloat4*>(bias)[q];
    vfloat4 ov = bv + dc * (a0 + a1 + a2 + a3 + dc * xc);
    __builtin_nontemporal_store(ov, reinterpret_cast<vfloat4*>(out)  + (size_t)node * 32 + q);
    __builtin_nontemporal_store(xc, reinterpret_cast<vfloat4*>(out2) + (size_t)node * 32 + q);
}

// =============================================================================

extern "C" void kernel_launch(void* const* d_in, const int* in_sizes, int n_in,
                              void* d_out, int out_size, void* d_ws, size_t ws_size,
                              hipStream_t stream) {
    const float* x    = (const float*)d_in[0];
    const int*   idx  = (const int*)d_in[1];   // [2, E]
    const float* bias = (const float*)d_in[2];

    const int n = in_sizes[0] / D;             // 50000
    const int e = in_sizes[1] / 2;             // 600000

    const int* row = idx;                      // sources
    const int* col = idx + e;                  // destinations

    float* out  = (float*)d_out;                     // [n, 128]
    float* out2 = (float*)d_out + (size_t)n * D;     // init_embeds

    const int nbN = (n + B - 1) / B;
    const int nbE = (e + B - 1) / B;
    const int aggB = (n * 32 + B - 1) / B;

    // ---- ELL + bf16 layout ----
    char* p0 = (char*)d_ws;
    int*  cursor  = (int*)p0;                        p0 += (size_t)n * 4;
    int*  spillCnt= (int*)p0;                        p0 += 16;
    int2* spill   = (int2*)p0;                       p0 += (size_t)SPILL_MAX * 8;
    p0 = (char*)(((uintptr_t)p0 + 15) & ~(uintptr_t)15);
    uint2* xb     = (uint2*)p0;                      p0 += (size_t)n * 32 * 8;   // bf16 x
    int*  ssrc    = (int*)p0;                        p0 += (size_t)n * WMAX * 4;
    size_t need_ell = (size_t)(p0 - (char*)d_ws);

    if (ws_size >= need_ell) {
        k_prep     <<<aggB, B, 0, stream>>>(x, out2, xb, cursor, spillCnt, n);
        k_place_ell<<<nbE,  B, 0, stream>>>(row, col, cursor, ssrc, spill, spillCnt, e);
        k_agg_ell  <<<aggB, B, 0, stream>>>(xb, bias, cursor, ssrc, out, n);
        k_spill    <<<(SPILL_MAX * 32) / B, B, 0, stream>>>(x, cursor, spill, spillCnt, out);
        return;
    }

    // ---- fallback: round-4 CSR pipeline ----
    char* p = (char*)d_ws;
    int*   degInt = (int*)p;            p += (size_t)n * 4;
    int*   cur2   = (int*)p;            p += (size_t)n * 4;
    int*   off    = (int*)p;            p += (size_t)(n + 1) * 4;
    int*   bsum   = (int*)p;            p += 256 * 4;
    float* dis    = (float*)p;          p += (size_t)n * 4;
    p = (char*)(((uintptr_t)p + 15) & ~(uintptr_t)15);
    int2*  pairs  = (int2*)p;

    k_zero <<<nbN, B, 0, stream>>>(degInt, n);
    k_count<<<nbE, B, 0, stream>>>(col, degInt, e);
    k_scan1<<<nbN, B, 0, stream>>>(degInt, off, bsum, n);
    k_scan2<<<1,   B, 0, stream>>>(bsum, nbN);
    k_scan3<<<nbN, B, 0, stream>>>(off, bsum, degInt, dis, cur2, n, e);
    k_place_pairs<<<nbE, B, 0, stream>>>(row, col, dis, cur2, pairs, e);
    k_aggregate_pairs<<<aggB, B, 0, stream>>>(x, bias, dis, off, pairs, out, out2, n);
}

// Round 6
// 81.908 us; speedup vs baseline: 12.9854x; 1.0296x over previous
//
#include <hip/hip_runtime.h>

#define D 128
#define B 256
#define WMAX 64
#define SPILL_MAX 8192
#define UPL 4   // placement unroll

typedef float vfloat4 __attribute__((ext_vector_type(4)));

// ---------------------------------------------------------------------------
// GCN message passing, ELL + bf16-gather edition:
//   prep : cursor=0, out2=x (NT), xb=bf16(x)
//   place: pos = cursor[c]++;  ssrc[c*64+pos] = r   (spill list if pos>=64)
//          x4-unrolled: 4 independent atomics in flight per thread
//   agg  : out[c] = bias + dc*( sum_j rsqrt(deg_rj+1)*xb[r_j] + dc*xb[c] ),
//          dc = rsqrt(cursor[c]+1); spill edges folded in (scan tiny list
//          only for nodes with cnt > WMAX — normally none)
// Fallback (small ws): round-4 CSR-pairs pipeline.
// ---------------------------------------------------------------------------

__device__ __forceinline__ unsigned short f2bf(float f) {   // RTNE f32->bf16
    unsigned u = __float_as_uint(f);
    u = u + 0x7FFFu + ((u >> 16) & 1u);
    return (unsigned short)(u >> 16);
}

__device__ __forceinline__ vfloat4 bf2f4(uint2 v) {
    vfloat4 r;
    r.x = __uint_as_float(v.x << 16);
    r.y = __uint_as_float(v.x & 0xffff0000u);
    r.z = __uint_as_float(v.y << 16);
    r.w = __uint_as_float(v.y & 0xffff0000u);
    return r;
}

__global__ void k_prep(const float* __restrict__ x, float* __restrict__ out2,
                       uint2* __restrict__ xb, int* __restrict__ cursor,
                       int* __restrict__ spillCnt, int n) {
    int gid = blockIdx.x * blockDim.x + threadIdx.x;
    if (gid == 0) *spillCnt = 0;
    if (gid < n) cursor[gid] = 0;
    if (gid >= n * 32) return;
    vfloat4 xv = reinterpret_cast<const vfloat4*>(x)[gid];
    __builtin_nontemporal_store(xv, reinterpret_cast<vfloat4*>(out2) + gid);
    uint2 b;
    b.x = (unsigned)f2bf(xv.x) | ((unsigned)f2bf(xv.y) << 16);
    b.y = (unsigned)f2bf(xv.z) | ((unsigned)f2bf(xv.w) << 16);
    xb[gid] = b;
}

// Each thread handles UPL edges strided by total thread count:
// batch loads -> batch independent atomics -> batch stores.
__global__ void k_place_ell(const int* __restrict__ row, const int* __restrict__ col,
                            int* __restrict__ cursor, int* __restrict__ ssrc,
                            int2* __restrict__ spill, int* __restrict__ spillCnt, int e) {
    int t = blockIdx.x * blockDim.x + threadIdx.x;
    int T = gridDim.x * blockDim.x;

    int r[UPL], c[UPL], p[UPL];
#pragma unroll
    for (int u = 0; u < UPL; ++u) {
        int i = t + u * T;
        bool v = (i < e);
        r[u] = v ? row[i] : -1;
        c[u] = v ? col[i] : 0;
    }
#pragma unroll
    for (int u = 0; u < UPL; ++u)
        p[u] = (r[u] >= 0) ? atomicAdd(&cursor[c[u]], 1) : 0;
#pragma unroll
    for (int u = 0; u < UPL; ++u) {
        if (r[u] < 0) continue;
        if (p[u] < WMAX) {
            ssrc[c[u] * WMAX + p[u]] = r[u];
        } else {
            int s = atomicAdd(spillCnt, 1);
            if (s < SPILL_MAX) spill[s] = make_int2(r[u], c[u]);
        }
    }
}

// 32 lanes per node, 8B bf16 gather per lane, x4 unrolled; spill folded in.
__global__ void k_agg_ell(const uint2* __restrict__ xb, const float* __restrict__ bias,
                          const int* __restrict__ cursor, const int* __restrict__ ssrc,
                          const int2* __restrict__ spill, const int* __restrict__ spillCnt,
                          float* __restrict__ out, int n) {
    int gid = blockIdx.x * blockDim.x + threadIdx.x;
    if (gid >= n * 32) return;
    int node = gid >> 5;
    int q    = gid & 31;

    int cnt = cursor[node];
    int m   = min(cnt, WMAX);
    const int* sp = ssrc + node * WMAX;

    vfloat4 a0 = {0.f, 0.f, 0.f, 0.f};
    vfloat4 a1 = a0, a2 = a0, a3 = a0;

    int j = 0;
    for (; j + 4 <= m; j += 4) {
        int r0 = sp[j + 0], r1 = sp[j + 1], r2 = sp[j + 2], r3 = sp[j + 3];
        uint2 v0 = xb[(size_t)r0 * 32 + q];
        uint2 v1 = xb[(size_t)r1 * 32 + q];
        uint2 v2 = xb[(size_t)r2 * 32 + q];
        uint2 v3 = xb[(size_t)r3 * 32 + q];
        float w0 = rsqrtf((float)cursor[r0] + 1.0f);
        float w1 = rsqrtf((float)cursor[r1] + 1.0f);
        float w2 = rsqrtf((float)cursor[r2] + 1.0f);
        float w3 = rsqrtf((float)cursor[r3] + 1.0f);
        a0 += w0 * bf2f4(v0);
        a1 += w1 * bf2f4(v1);
        a2 += w2 * bf2f4(v2);
        a3 += w3 * bf2f4(v3);
    }
    for (; j < m; ++j) {
        int r = sp[j];
        uint2 v = xb[(size_t)r * 32 + q];
        float w = rsqrtf((float)cursor[r] + 1.0f);
        a0 += w * bf2f4(v);
    }

    // Overflow edges (normally zero): scan the tiny spill list.
    if (cnt > WMAX) {
        int sc = min(*spillCnt, SPILL_MAX);
        for (int s = 0; s < sc; ++s) {
            int2 pr = spill[s];
            if (pr.y == node) {
                float w = rsqrtf((float)cursor[pr.x] + 1.0f);
                a0 += w * bf2f4(xb[(size_t)pr.x * 32 + q]);
            }
        }
    }

    float dc = rsqrtf((float)cnt + 1.0f);
    vfloat4 xc = bf2f4(xb[(size_t)node * 32 + q]);
    vfloat4 bv = reinterpret_cast<const vfloat4*>(bias)[q];
    vfloat4 ov = bv + dc * (a0 + a1 + a2 + a3 + dc * xc);

    __builtin_nontemporal_store(ov, reinterpret_cast<vfloat4*>(out) + (size_t)node * 32 + q);
}

// ======================= fallback: round-4 CSR pipeline =======================

__global__ void k_zero(int* __restrict__ degInt, int n) {
    int i = blockIdx.x * blockDim.x + threadIdx.x;
    if (i < n) degInt[i] = 0;
}

__global__ void k_count(const int* __restrict__ col, int* __restrict__ degInt, int e) {
    int i = blockIdx.x * blockDim.x + threadIdx.x;
    if (i < e) atomicAdd(&degInt[col[i]], 1);
}

__global__ void k_scan1(const int* __restrict__ degInt, int* __restrict__ off,
                        int* __restrict__ bsum, int n) {
    __shared__ int sm[B];
    int i = blockIdx.x * B + threadIdx.x;
    int v = (i < n) ? degInt[i] : 0;
    sm[threadIdx.x] = v;
    __syncthreads();
    for (int s = 1; s < B; s <<= 1) {
        int t = (threadIdx.x >= (unsigned)s) ? sm[threadIdx.x - s] : 0;
        __syncthreads();
        sm[threadIdx.x] += t;
        __syncthreads();
    }
    if (i < n) off[i] = sm[threadIdx.x] - v;
    if (threadIdx.x == B - 1) bsum[blockIdx.x] = sm[B - 1];
}

__global__ void k_scan2(int* __restrict__ bsum, int nb) {
    __shared__ int sm[B];
    int v = (threadIdx.x < (unsigned)nb) ? bsum[threadIdx.x] : 0;
    sm[threadIdx.x] = v;
    __syncthreads();
    for (int s = 1; s < B; s <<= 1) {
        int t = (threadIdx.x >= (unsigned)s) ? sm[threadIdx.x - s] : 0;
        __syncthreads();
        sm[threadIdx.x] += t;
        __syncthreads();
    }
    if (threadIdx.x < (unsigned)nb) bsum[threadIdx.x] = sm[threadIdx.x] - v;
}

__global__ void k_scan3(int* __restrict__ off, const int* __restrict__ bsum,
                        const int* __restrict__ degInt, float* __restrict__ dis,
                        int* __restrict__ cursor, int n, int e) {
    int i = blockIdx.x * B + threadIdx.x;
    if (i < n) {
        int o = off[i] + bsum[blockIdx.x];
        off[i] = o;
        cursor[i] = o;
        dis[i] = rsqrtf((float)degInt[i] + 1.0f);
    }
    if (i == 0) off[n] = e;
}

__global__ void k_place_pairs(const int* __restrict__ row, const int* __restrict__ col,
                              const float* __restrict__ dis, int* __restrict__ cursor,
                              int2* __restrict__ pairs, int e) {
    int i = blockIdx.x * blockDim.x + threadIdx.x;
    if (i >= e) return;
    int r = row[i];
    int c = col[i];
    float w = dis[r];
    int pos = atomicAdd(&cursor[c], 1);
    pairs[pos] = make_int2(r, __float_as_int(w));
}

__global__ void k_aggregate_pairs(const float* __restrict__ x, const float* __restrict__ bias,
                                  const float* __restrict__ dis, const int* __restrict__ off,
                                  const int2* __restrict__ pairs, float* __restrict__ out,
                                  float* __restrict__ out2, int n) {
    int gid = blockIdx.x * blockDim.x + threadIdx.x;
    if (gid >= n * 32) return;
    int node = gid >> 5;
    int q    = gid & 31;
    const vfloat4* x4 = reinterpret_cast<const vfloat4*>(x);
    int j   = off[node];
    int end = off[node + 1];
    vfloat4 a0 = {0.f, 0.f, 0.f, 0.f};
    vfloat4 a1 = a0, a2 = a0, a3 = a0;
    for (; j + 4 <= end; j += 4) {
        int2 p0 = pairs[j + 0];
        int2 p1 = pairs[j + 1];
        int2 p2 = pairs[j + 2];
        int2 p3 = pairs[j + 3];
        vfloat4 v0 = x4[(size_t)p0.x * 32 + q];
        vfloat4 v1 = x4[(size_t)p1.x * 32 + q];
        vfloat4 v2 = x4[(size_t)p2.x * 32 + q];
        vfloat4 v3 = x4[(size_t)p3.x * 32 + q];
        a0 += __int_as_float(p0.y) * v0;
        a1 += __int_as_float(p1.y) * v1;
        a2 += __int_as_float(p2.y) * v2;
        a3 += __int_as_float(p3.y) * v3;
    }
    for (; j < end; ++j) {
        int2 p = pairs[j];
        a0 += __int_as_float(p.y) * x4[(size_t)p.x * 32 + q];
    }
    float dc = dis[node];
    vfloat4 xc = x4[(size_t)node * 32 + q];
    vfloat4 bv = reinterpret_cast<const vfloat4*>(bias)[q];
    vfloat4 ov = bv + dc * (a0 + a1 + a2 + a3 + dc * xc);
    __builtin_nontemporal_store(ov, reinterpret_cast<vfloat4*>(out)  + (size_t)node * 32 + q);
    __builtin_nontemporal_store(xc, reinterpret_cast<vfloat4*>(out2) + (size_t)node * 32 + q);
}

// =============================================================================

extern "C" void kernel_launch(void* const* d_in, const int* in_sizes, int n_in,
                              void* d_out, int out_size, void* d_ws, size_t ws_size,
                              hipStream_t stream) {
    const float* x    = (const float*)d_in[0];
    const int*   idx  = (const int*)d_in[1];   // [2, E]
    const float* bias = (const float*)d_in[2];

    const int n = in_sizes[0] / D;             // 50000
    const int e = in_sizes[1] / 2;             // 600000

    const int* row = idx;                      // sources
    const int* col = idx + e;                  // destinations

    float* out  = (float*)d_out;                     // [n, 128]
    float* out2 = (float*)d_out + (size_t)n * D;     // init_embeds

    const int nbN = (n + B - 1) / B;
    const int nbE = (e + B - 1) / B;
    const int aggB = (n * 32 + B - 1) / B;

    // ---- ELL + bf16 layout ----
    char* p0 = (char*)d_ws;
    int*  cursor  = (int*)p0;                        p0 += (size_t)n * 4;
    int*  spillCnt= (int*)p0;                        p0 += 16;
    int2* spill   = (int2*)p0;                       p0 += (size_t)SPILL_MAX * 8;
    p0 = (char*)(((uintptr_t)p0 + 15) & ~(uintptr_t)15);
    uint2* xb     = (uint2*)p0;                      p0 += (size_t)n * 32 * 8;   // bf16 x
    int*  ssrc    = (int*)p0;                        p0 += (size_t)n * WMAX * 4;
    size_t need_ell = (size_t)(p0 - (char*)d_ws);

    if (ws_size >= need_ell) {
        const int plB = (e + B * UPL - 1) / (B * UPL);   // ~586 blocks
        k_prep     <<<aggB, B, 0, stream>>>(x, out2, xb, cursor, spillCnt, n);
        k_place_ell<<<plB,  B, 0, stream>>>(row, col, cursor, ssrc, spill, spillCnt, e);
        k_agg_ell  <<<aggB, B, 0, stream>>>(xb, bias, cursor, ssrc, spill, spillCnt, out, n);
        return;
    }

    // ---- fallback: round-4 CSR pipeline ----
    char* p = (char*)d_ws;
    int*   degInt = (int*)p;            p += (size_t)n * 4;
    int*   cur2   = (int*)p;            p += (size_t)n * 4;
    int*   off    = (int*)p;            p += (size_t)(n + 1) * 4;
    int*   bsum   = (int*)p;            p += 256 * 4;
    float* dis    = (float*)p;          p += (size_t)n * 4;
    p = (char*)(((uintptr_t)p + 15) & ~(uintptr_t)15);
    int2*  pairs  = (int2*)p;

    k_zero <<<nbN, B, 0, stream>>>(degInt, n);
    k_count<<<nbE, B, 0, stream>>>(col, degInt, e);
    k_scan1<<<nbN, B, 0, stream>>>(degInt, off, bsum, n);
    k_scan2<<<1,   B, 0, stream>>>(bsum, nbN);
    k_scan3<<<nbN, B, 0, stream>>>(off, bsum, degInt, dis, cur2, n, e);
    k_place_pairs<<<nbE, B, 0, stream>>>(row, col, dis, cur2, pairs, e);
    k_aggregate_pairs<<<aggB, B, 0, stream>>>(x, bias, dis, off, pairs, out, out2, n);
}

// Round 7
// 77.103 us; speedup vs baseline: 13.7947x; 1.0623x over previous
//
#include <hip/hip_runtime.h>

#define D 128
#define B 256
#define WMAX 64
#define SPILL_MAX 8192
#define NPART 8   // XCD count on MI355X; blockIdx % 8 ~ XCD (perf heuristic only)

typedef float vfloat4 __attribute__((ext_vector_type(4)));

// ---------------------------------------------------------------------------
// GCN message passing, ELL + bf16-gather + XCD-partitioned build:
//   prep : cursor=0, out2=x (NT), xb=bf16(x)
//   place: 8 block-groups (one per XCD); group p scans ALL edges, keeps only
//          destinations in node range [n*p/8, n*(p+1)/8)  ->  cursor atomics
//          and ssrc stores stay in that XCD's L2 (no cross-XCD line bounce).
//   agg  : blocks remapped so node range p is processed by blockIdx%8==p;
//          out[c] = bias + dc*( sum_j rsqrt(deg_rj+1)*xb[r_j] + dc*xb[c] )
//   spill edges (deg > WMAX, normally none) folded into agg.
// Fallback (small ws): round-4 CSR-pairs pipeline.
// ---------------------------------------------------------------------------

__device__ __forceinline__ unsigned short f2bf(float f) {   // RTNE f32->bf16
    unsigned u = __float_as_uint(f);
    u = u + 0x7FFFu + ((u >> 16) & 1u);
    return (unsigned short)(u >> 16);
}

__device__ __forceinline__ vfloat4 bf2f4(uint2 v) {
    vfloat4 r;
    r.x = __uint_as_float(v.x << 16);
    r.y = __uint_as_float(v.x & 0xffff0000u);
    r.z = __uint_as_float(v.y << 16);
    r.w = __uint_as_float(v.y & 0xffff0000u);
    return r;
}

__global__ void k_prep(const float* __restrict__ x, float* __restrict__ out2,
                       uint2* __restrict__ xb, int* __restrict__ cursor,
                       int* __restrict__ spillCnt, int n) {
    int gid = blockIdx.x * blockDim.x + threadIdx.x;
    if (gid == 0) *spillCnt = 0;
    if (gid < n) cursor[gid] = 0;
    if (gid >= n * 32) return;
    vfloat4 xv = reinterpret_cast<const vfloat4*>(x)[gid];
    __builtin_nontemporal_store(xv, reinterpret_cast<vfloat4*>(out2) + gid);
    uint2 b;
    b.x = (unsigned)f2bf(xv.x) | ((unsigned)f2bf(xv.y) << 16);
    b.y = (unsigned)f2bf(xv.z) | ((unsigned)f2bf(xv.w) << 16);
    xb[gid] = b;
}

// Block-group p (= blockIdx%8, tracking the XCD round-robin) scans the whole
// edge list and places only destinations in its node range. col reads are
// coalesced; 7/8 of lanes drop out cheaply; ssrc/cursor traffic is XCD-local.
__global__ void k_place_ell(const int* __restrict__ row, const int* __restrict__ col,
                            int* __restrict__ cursor, int* __restrict__ ssrc,
                            int2* __restrict__ spill, int* __restrict__ spillCnt,
                            int e, int n) {
    int p  = blockIdx.x & (NPART - 1);
    int bg = blockIdx.x >> 3;                       // block index within group
    int tg = bg * blockDim.x + threadIdx.x;         // thread index within group
    int T  = (gridDim.x >> 3) * blockDim.x;         // threads per group
    int lo = (int)((long long)n * p / NPART);
    int hi = (int)((long long)n * (p + 1) / NPART);

    for (int i = tg; i < e; i += T) {
        int c = col[i];
        if (c < lo || c >= hi) continue;
        int r = row[i];
        int pos = atomicAdd(&cursor[c], 1);
        if (pos < WMAX) {
            ssrc[c * WMAX + pos] = r;
        } else {
            int s = atomicAdd(spillCnt, 1);
            if (s < SPILL_MAX) spill[s] = make_int2(r, c);
        }
    }
}

// 32 lanes per node, 8B bf16 gather per lane, x4 unrolled; spill folded in.
// Blocks remapped so node range p is handled by blocks with blockIdx%8==p
// (ssrc/cursor lines are already dirty-resident in that XCD's L2).
__global__ void k_agg_ell(const uint2* __restrict__ xb, const float* __restrict__ bias,
                          const int* __restrict__ cursor, const int* __restrict__ ssrc,
                          const int2* __restrict__ spill, const int* __restrict__ spillCnt,
                          float* __restrict__ out, int n) {
    int bpg = (gridDim.x + NPART - 1) >> 3;                    // blocks per group
    int node_block = (blockIdx.x & (NPART - 1)) * bpg + (blockIdx.x >> 3);
    int node = node_block * 8 + (threadIdx.x >> 5);
    if (node >= n) return;
    int q = threadIdx.x & 31;

    int cnt = cursor[node];
    int m   = min(cnt, WMAX);
    const int* sp = ssrc + node * WMAX;

    vfloat4 a0 = {0.f, 0.f, 0.f, 0.f};
    vfloat4 a1 = a0, a2 = a0, a3 = a0;

    int j = 0;
    for (; j + 4 <= m; j += 4) {
        int r0 = sp[j + 0], r1 = sp[j + 1], r2 = sp[j + 2], r3 = sp[j + 3];
        uint2 v0 = xb[(size_t)r0 * 32 + q];
        uint2 v1 = xb[(size_t)r1 * 32 + q];
        uint2 v2 = xb[(size_t)r2 * 32 + q];
        uint2 v3 = xb[(size_t)r3 * 32 + q];
        float w0 = rsqrtf((float)cursor[r0] + 1.0f);
        float w1 = rsqrtf((float)cursor[r1] + 1.0f);
        float w2 = rsqrtf((float)cursor[r2] + 1.0f);
        float w3 = rsqrtf((float)cursor[r3] + 1.0f);
        a0 += w0 * bf2f4(v0);
        a1 += w1 * bf2f4(v1);
        a2 += w2 * bf2f4(v2);
        a3 += w3 * bf2f4(v3);
    }
    for (; j < m; ++j) {
        int r = sp[j];
        uint2 v = xb[(size_t)r * 32 + q];
        float w = rsqrtf((float)cursor[r] + 1.0f);
        a0 += w * bf2f4(v);
    }

    // Overflow edges (normally zero): scan the tiny spill list.
    if (cnt > WMAX) {
        int sc = min(*spillCnt, SPILL_MAX);
        for (int s = 0; s < sc; ++s) {
            int2 pr = spill[s];
            if (pr.y == node) {
                float w = rsqrtf((float)cursor[pr.x] + 1.0f);
                a0 += w * bf2f4(xb[(size_t)pr.x * 32 + q]);
            }
        }
    }

    float dc = rsqrtf((float)cnt + 1.0f);
    vfloat4 xc = bf2f4(xb[(size_t)node * 32 + q]);
    vfloat4 bv = reinterpret_cast<const vfloat4*>(bias)[q];
    vfloat4 ov = bv + dc * (a0 + a1 + a2 + a3 + dc * xc);

    __builtin_nontemporal_store(ov, reinterpret_cast<vfloat4*>(out) + (size_t)node * 32 + q);
}

// ======================= fallback: round-4 CSR pipeline =======================

__global__ void k_zero(int* __restrict__ degInt, int n) {
    int i = blockIdx.x * blockDim.x + threadIdx.x;
    if (i < n) degInt[i] = 0;
}

__global__ void k_count(const int* __restrict__ col, int* __restrict__ degInt, int e) {
    int i = blockIdx.x * blockDim.x + threadIdx.x;
    if (i < e) atomicAdd(&degInt[col[i]], 1);
}

__global__ void k_scan1(const int* __restrict__ degInt, int* __restrict__ off,
                        int* __restrict__ bsum, int n) {
    __shared__ int sm[B];
    int i = blockIdx.x * B + threadIdx.x;
    int v = (i < n) ? degInt[i] : 0;
    sm[threadIdx.x] = v;
    __syncthreads();
    for (int s = 1; s < B; s <<= 1) {
        int t = (threadIdx.x >= (unsigned)s) ? sm[threadIdx.x - s] : 0;
        __syncthreads();
        sm[threadIdx.x] += t;
        __syncthreads();
    }
    if (i < n) off[i] = sm[threadIdx.x] - v;
    if (threadIdx.x == B - 1) bsum[blockIdx.x] = sm[B - 1];
}

__global__ void k_scan2(int* __restrict__ bsum, int nb) {
    __shared__ int sm[B];
    int v = (threadIdx.x < (unsigned)nb) ? bsum[threadIdx.x] : 0;
    sm[threadIdx.x] = v;
    __syncthreads();
    for (int s = 1; s < B; s <<= 1) {
        int t = (threadIdx.x >= (unsigned)s) ? sm[threadIdx.x - s] : 0;
        __syncthreads();
        sm[threadIdx.x] += t;
        __syncthreads();
    }
    if (threadIdx.x < (unsigned)nb) bsum[threadIdx.x] = sm[threadIdx.x] - v;
}

__global__ void k_scan3(int* __restrict__ off, const int* __restrict__ bsum,
                        const int* __restrict__ degInt, float* __restrict__ dis,
                        int* __restrict__ cursor, int n, int e) {
    int i = blockIdx.x * B + threadIdx.x;
    if (i < n) {
        int o = off[i] + bsum[blockIdx.x];
        off[i] = o;
        cursor[i] = o;
        dis[i] = rsqrtf((float)degInt[i] + 1.0f);
    }
    if (i == 0) off[n] = e;
}

__global__ void k_place_pairs(const int* __restrict__ row, const int* __restrict__ col,
                              const float* __restrict__ dis, int* __restrict__ cursor,
                              int2* __restrict__ pairs, int e) {
    int i = blockIdx.x * blockDim.x + threadIdx.x;
    if (i >= e) return;
    int r = row[i];
    int c = col[i];
    float w = dis[r];
    int pos = atomicAdd(&cursor[c], 1);
    pairs[pos] = make_int2(r, __float_as_int(w));
}

__global__ void k_aggregate_pairs(const float* __restrict__ x, const float* __restrict__ bias,
                                  const float* __restrict__ dis, const int* __restrict__ off,
                                  const int2* __restrict__ pairs, float* __restrict__ out,
                                  float* __restrict__ out2, int n) {
    int gid = blockIdx.x * blockDim.x + threadIdx.x;
    if (gid >= n * 32) return;
    int node = gid >> 5;
    int q    = gid & 31;
    const vfloat4* x4 = reinterpret_cast<const vfloat4*>(x);
    int j   = off[node];
    int end = off[node + 1];
    vfloat4 a0 = {0.f, 0.f, 0.f, 0.f};
    vfloat4 a1 = a0, a2 = a0, a3 = a0;
    for (; j + 4 <= end; j += 4) {
        int2 p0 = pairs[j + 0];
        int2 p1 = pairs[j + 1];
        int2 p2 = pairs[j + 2];
        int2 p3 = pairs[j + 3];
        vfloat4 v0 = x4[(size_t)p0.x * 32 + q];
        vfloat4 v1 = x4[(size_t)p1.x * 32 + q];
        vfloat4 v2 = x4[(size_t)p2.x * 32 + q];
        vfloat4 v3 = x4[(size_t)p3.x * 32 + q];
        a0 += __int_as_float(p0.y) * v0;
        a1 += __int_as_float(p1.y) * v1;
        a2 += __int_as_float(p2.y) * v2;
        a3 += __int_as_float(p3.y) * v3;
    }
    for (; j < end; ++j) {
        int2 p = pairs[j];
        a0 += __int_as_float(p.y) * x4[(size_t)p.x * 32 + q];
    }
    float dc = dis[node];
    vfloat4 xc = x4[(size_t)node * 32 + q];
    vfloat4 bv = reinterpret_cast<const vfloat4*>(bias)[q];
    vfloat4 ov = bv + dc * (a0 + a1 + a2 + a3 + dc * xc);
    __builtin_nontemporal_store(ov, reinterpret_cast<vfloat4*>(out)  + (size_t)node * 32 + q);
    __builtin_nontemporal_store(xc, reinterpret_cast<vfloat4*>(out2) + (size_t)node * 32 + q);
}

// =============================================================================

extern "C" void kernel_launch(void* const* d_in, const int* in_sizes, int n_in,
                              void* d_out, int out_size, void* d_ws, size_t ws_size,
                              hipStream_t stream) {
    const float* x    = (const float*)d_in[0];
    const int*   idx  = (const int*)d_in[1];   // [2, E]
    const float* bias = (const float*)d_in[2];

    const int n = in_sizes[0] / D;             // 50000
    const int e = in_sizes[1] / 2;             // 600000

    const int* row = idx;                      // sources
    const int* col = idx + e;                  // destinations

    float* out  = (float*)d_out;                     // [n, 128]
    float* out2 = (float*)d_out + (size_t)n * D;     // init_embeds

    const int nbN = (n + B - 1) / B;
    const int nbE = (e + B - 1) / B;
    const int aggB = (n * 32 + B - 1) / B;

    // ---- ELL + bf16 layout ----
    char* p0 = (char*)d_ws;
    int*  cursor  = (int*)p0;                        p0 += (size_t)n * 4;
    int*  spillCnt= (int*)p0;                        p0 += 16;
    int2* spill   = (int2*)p0;                       p0 += (size_t)SPILL_MAX * 8;
    p0 = (char*)(((uintptr_t)p0 + 15) & ~(uintptr_t)15);
    uint2* xb     = (uint2*)p0;                      p0 += (size_t)n * 32 * 8;   // bf16 x
    int*  ssrc    = (int*)p0;                        p0 += (size_t)n * WMAX * 4;
    size_t need_ell = (size_t)(p0 - (char*)d_ws);

    if (ws_size >= need_ell) {
        // place: 2048 blocks = 8 XCD groups x 256 blocks, all co-resident.
        const int plB = 2048;
        // agg: blocks of 8 nodes, remapped so partition p gets blockIdx%8==p.
        const int bpg  = (n + 8 * NPART - 1) / (8 * NPART);  // blocks per group
        const int agB  = bpg * NPART;
        k_prep     <<<aggB, B, 0, stream>>>(x, out2, xb, cursor, spillCnt, n);
        k_place_ell<<<plB,  B, 0, stream>>>(row, col, cursor, ssrc, spill, spillCnt, e, n);
        k_agg_ell  <<<agB,  B, 0, stream>>>(xb, bias, cursor, ssrc, spill, spillCnt, out, n);
        return;
    }

    // ---- fallback: round-4 CSR pipeline ----
    char* p = (char*)d_ws;
    int*   degInt = (int*)p;            p += (size_t)n * 4;
    int*   cur2   = (int*)p;            p += (size_t)n * 4;
    int*   off    = (int*)p;            p += (size_t)(n + 1) * 4;
    int*   bsum   = (int*)p;            p += 256 * 4;
    float* dis    = (float*)p;          p += (size_t)n * 4;
    p = (char*)(((uintptr_t)p + 15) & ~(uintptr_t)15);
    int2*  pairs  = (int2*)p;

    k_zero <<<nbN, B, 0, stream>>>(degInt, n);
    k_count<<<nbE, B, 0, stream>>>(col, degInt, e);
    k_scan1<<<nbN, B, 0, stream>>>(degInt, off, bsum, n);
    k_scan2<<<1,   B, 0, stream>>>(bsum, nbN);
    k_scan3<<<nbN, B, 0, stream>>>(off, bsum, degInt, dis, cur2, n, e);
    k_place_pairs<<<nbE, B, 0, stream>>>(row, col, dis, cur2, pairs, e);
    k_aggregate_pairs<<<aggB, B, 0, stream>>>(x, bias, dis, off, pairs, out, out2, n);
}